// Round 6
// baseline (365.046 us; speedup 1.0000x reference)
//
#include <hip/hip_runtime.h>

#define NN 50000
#define NE 500000
#define FIN 16
#define FOUT 16
#define HID 64
#define JCH 13        // W2R j-chunk for LDS staging: 65 = 5*13
#define NLB 8         // src nodes per fused block
#define TLR 1044      // LDS T-row stride (floats): pad 1040->1044 so sl*20%32 is a bank permutation

typedef unsigned int uint;

// ===========================================================================
// MAIN PATH. Factorized msg[e,o] = T[s][64][o] + sum_j h_j*T[s][j][o], with
// T computed PER BLOCK into LDS (fp32) and consumed immediately by that
// block's src-sorted edges. T never touches HBM (round-5 lesson: the 104MB
// T round-trip + LDS-read volume dominated; fp32 LDS tile also kills the
// bf16 unpack ops in the edge loop).
// ===========================================================================

// W2R[j][o][i] = W2[j][i*16+o] (j<64), b2[i*16+o] (j==64)
__global__ __launch_bounds__(256) void w2r_prep(
    const float* __restrict__ W2, const float* __restrict__ b2,
    float* __restrict__ W2R)
{
    const int t = blockIdx.x * blockDim.x + threadIdx.x;
    if (t >= 65 * 256) return;
    const int j = t >> 8;
    const int col = t & 255;          // col = i*16 + o
    const int i = col >> 4, o = col & 15;
    const float v = (j < 64) ? W2[j * 256 + col] : b2[col];
    W2R[j * 256 + o * 16 + i] = v;
}

// one pass: src ranks (for src-sort) + dst degree histogram
__global__ __launch_bounds__(256) void count_both(
    const int* __restrict__ src, const int* __restrict__ dst,
    int* __restrict__ deg_s, int* __restrict__ pos_s, int* __restrict__ deg_d)
{
    const int e = blockIdx.x * blockDim.x + threadIdx.x;
    if (e >= NE) return;
    pos_s[e] = atomicAdd(deg_s + src[e], 1);
    atomicAdd(deg_d + dst[e], 1);
}

// two independent exclusive scans (block 0: A, block 1: B), n=NN each
__global__ __launch_bounds__(1024) void dgc_scan2(
    const int* __restrict__ degA, int* __restrict__ offA,
    const int* __restrict__ degB, int* __restrict__ offB)
{
    const int* __restrict__ deg = blockIdx.x ? degB : degA;
    int* __restrict__ offs      = blockIdx.x ? offB : offA;
    __shared__ int wsum[16];
    const int tid = threadIdx.x;
    const int lane = tid & 63;
    const int wid = tid >> 6;
    int carry = 0;
    for (int base = 0; base < NN; base += 1024) {
        const int idx = base + tid;
        const int v = (idx < NN) ? deg[idx] : 0;
        int s = v;
        #pragma unroll
        for (int d = 1; d < 64; d <<= 1) {
            int t = __shfl_up(s, d, 64);
            if (lane >= d) s += t;
        }
        if (lane == 63) wsum[wid] = s;
        __syncthreads();
        if (wid == 0 && lane < 16) {
            int w = wsum[lane];
            #pragma unroll
            for (int d = 1; d < 16; d <<= 1) {
                int t = __shfl_up(w, d, 64);
                if (lane >= d) w += t;
            }
            wsum[lane] = w;
        }
        __syncthreads();
        const int wpre = (wid == 0) ? 0 : wsum[wid - 1];
        if (idx < NN) offs[idx] = carry + wpre + (s - v);
        carry += wsum[15];
        __syncthreads();
    }
    if (tid == 0) offs[NN] = carry;
}

__global__ __launch_bounds__(256) void scatter_src(
    const int* __restrict__ src, const int* __restrict__ pos_s,
    const int* __restrict__ offs_s, int* __restrict__ eidx_s)
{
    const int e = blockIdx.x * blockDim.x + threadIdx.x;
    if (e >= NE) return;
    eidx_s[offs_s[src[e]] + pos_s[e]] = e;
}

// Fused: Phase A computes T-tile for NLB src nodes into LDS (fp32);
// Phase B runs the per-edge MLP against the LDS tile and writes the message
// directly to its dst-sorted slot.
__global__ __launch_bounds__(256) void fused_edge(
    const float* __restrict__ x, const float* __restrict__ ef,
    const int* __restrict__ src, const int* __restrict__ dst,
    const float* __restrict__ W1, const float* __restrict__ b1,
    const float* __restrict__ W2R, const int* __restrict__ eidx_s,
    const int* __restrict__ offs_s, const int* __restrict__ offs_d,
    int* __restrict__ cur_d, float* __restrict__ msgbuf)
{
    __shared__ __align__(16) float tl[NLB * TLR];        // 33,408 B
    __shared__ __align__(16) float w2s[JCH * 16 * 20];   // 16,640 B  [jj][o][20]
    const int tid = threadIdx.x;
    const int n0 = blockIdx.x * NLB;

    // ---------------- Phase A: T-tile -> LDS ----------------
    // thread = (nl, o, sub): nl = tid>>5 (0..7), o = (tid>>1)&15, sub = tid&1
    {
        const int nl  = tid >> 5;
        const int o   = (tid >> 1) & 15;
        const int sub = tid & 1;

        float xr[16];
        {
            const float4* p = reinterpret_cast<const float4*>(x) + (size_t)(n0 + nl) * 4;
            float4 a = p[0], b = p[1], c = p[2], d = p[3];
            xr[0]=a.x; xr[1]=a.y; xr[2]=a.z;  xr[3]=a.w;
            xr[4]=b.x; xr[5]=b.y; xr[6]=b.z;  xr[7]=b.w;
            xr[8]=c.x; xr[9]=c.y; xr[10]=c.z; xr[11]=c.w;
            xr[12]=d.x; xr[13]=d.y; xr[14]=d.z; xr[15]=d.w;
        }

        for (int c = 0; c < 5; ++c) {
            const int j0 = c * JCH;
            // stage 13 j-rows of W2R (coalesced) into padded LDS
            for (int g = tid; g < JCH * 256; g += 256) {
                const int jj = g >> 8;
                const int col = g & 255;      // col = oo*16 + ii
                const int oo = col >> 4, ii = col & 15;
                w2s[jj * 320 + oo * 20 + ii] = W2R[(size_t)(j0 + jj) * 256 + col];
            }
            __syncthreads();

            const int jb = sub ? 7 : 0;
            const int je = sub ? JCH : 7;
            for (int jj = jb; jj < je; ++jj) {
                const float4* wp = reinterpret_cast<const float4*>(w2s + jj * 320 + o * 20);
                float4 wa = wp[0], wb = wp[1], wc = wp[2], wd = wp[3];
                float s;
                s  = xr[0]*wa.x;           s = fmaf(xr[1],  wa.y, s); s = fmaf(xr[2],  wa.z, s); s = fmaf(xr[3],  wa.w, s);
                s = fmaf(xr[4],  wb.x, s); s = fmaf(xr[5],  wb.y, s); s = fmaf(xr[6],  wb.z, s); s = fmaf(xr[7],  wb.w, s);
                s = fmaf(xr[8],  wc.x, s); s = fmaf(xr[9],  wc.y, s); s = fmaf(xr[10], wc.z, s); s = fmaf(xr[11], wc.w, s);
                s = fmaf(xr[12], wd.x, s); s = fmaf(xr[13], wd.y, s); s = fmaf(xr[14], wd.z, s); s = fmaf(xr[15], wd.w, s);
                tl[nl * TLR + (j0 + jj) * 16 + o] = s;
            }
            __syncthreads();   // also the Phase-B barrier on the last chunk
        }
    }

    // ---------------- Phase B: edges of nodes [n0, n0+NLB) ----------------
    const int kbeg = offs_s[n0];
    const int kend = offs_s[n0 + NLB];
    for (int k = kbeg + tid; k < kend; k += 256) {
        const int e = eidx_s[k];
        const int sl = src[e] - n0;          // 0..NLB-1
        const float* tr = tl + sl * TLR;

        float efv[16];
        {
            const float4* p = reinterpret_cast<const float4*>(ef) + (size_t)e * 4;
            float4 a = p[0], b = p[1], c = p[2], d = p[3];
            efv[0]=a.x; efv[1]=a.y; efv[2]=a.z;  efv[3]=a.w;
            efv[4]=b.x; efv[5]=b.y; efv[6]=b.z;  efv[7]=b.w;
            efv[8]=c.x; efv[9]=c.y; efv[10]=c.z; efv[11]=c.w;
            efv[12]=d.x; efv[13]=d.y; efv[14]=d.z; efv[15]=d.w;
        }

        float m[16];
        {   // b2 row (j=64): tr + 1024
            const float4* bp = reinterpret_cast<const float4*>(tr + 1024);
            float4 a = bp[0], b = bp[1], c = bp[2], d = bp[3];
            m[0]=a.x; m[1]=a.y; m[2]=a.z;  m[3]=a.w;
            m[4]=b.x; m[5]=b.y; m[6]=b.z;  m[7]=b.w;
            m[8]=c.x; m[9]=c.y; m[10]=c.z; m[11]=c.w;
            m[12]=d.x; m[13]=d.y; m[14]=d.z; m[15]=d.w;
        }

        for (int j = 0; j < HID; ++j) {
            float hj = b1[j];
            #pragma unroll
            for (int i = 0; i < 16; ++i)
                hj = fmaf(efv[i], W1[i * HID + j], hj);
            hj = fmaxf(hj, 0.f);

            const float4* tp = reinterpret_cast<const float4*>(tr + j * 16);
            float4 a = tp[0], b = tp[1], c = tp[2], d = tp[3];
            m[0]  = fmaf(hj, a.x, m[0]);  m[1]  = fmaf(hj, a.y, m[1]);
            m[2]  = fmaf(hj, a.z, m[2]);  m[3]  = fmaf(hj, a.w, m[3]);
            m[4]  = fmaf(hj, b.x, m[4]);  m[5]  = fmaf(hj, b.y, m[5]);
            m[6]  = fmaf(hj, b.z, m[6]);  m[7]  = fmaf(hj, b.w, m[7]);
            m[8]  = fmaf(hj, c.x, m[8]);  m[9]  = fmaf(hj, c.y, m[9]);
            m[10] = fmaf(hj, c.z, m[10]); m[11] = fmaf(hj, c.w, m[11]);
            m[12] = fmaf(hj, d.x, m[12]); m[13] = fmaf(hj, d.y, m[13]);
            m[14] = fmaf(hj, d.z, m[14]); m[15] = fmaf(hj, d.w, m[15]);
        }

        const int d = dst[e];
        const int slot = offs_d[d] + atomicAdd(cur_d + d, 1);
        float4* mr = reinterpret_cast<float4*>(msgbuf + (size_t)slot * 16);
        mr[0] = make_float4(m[0], m[1], m[2], m[3]);
        mr[1] = make_float4(m[4], m[5], m[6], m[7]);
        mr[2] = make_float4(m[8], m[9], m[10], m[11]);
        mr[3] = make_float4(m[12], m[13], m[14], m[15]);
    }
}

// contiguous-range gather: 16 lanes per node stream deg*64B
__global__ __launch_bounds__(256) void gather_mean2(
    const float* __restrict__ msgbuf, const int* __restrict__ offs_d,
    const float* __restrict__ x, const float* __restrict__ bias,
    float* __restrict__ out)
{
    const int t = blockIdx.x * blockDim.x + threadIdx.x;
    if (t >= NN * FOUT) return;
    const int n = t >> 4;
    const int o = t & 15;
    const int beg = offs_d[n], end = offs_d[n + 1];
    float s = 0.f;
    for (int k = beg; k < end; ++k)
        s += msgbuf[(size_t)k * 16 + o];
    const int d = end - beg;
    const float v = (d > 0) ? (s / (float)d) : x[t];
    out[t] = v + bias[o];
}

// ===========================================================================
// FALLBACK (round-2 proven path, ~36.4 MB ws)
// ===========================================================================
__global__ __launch_bounds__(1024) void dgc_scan(
    const int* __restrict__ deg, int* __restrict__ offs, int n)
{
    __shared__ int wsum[16];
    const int tid = threadIdx.x;
    const int lane = tid & 63;
    const int wid = tid >> 6;
    int carry = 0;
    for (int base = 0; base < n; base += 1024) {
        const int idx = base + tid;
        const int v = (idx < n) ? deg[idx] : 0;
        int s = v;
        #pragma unroll
        for (int d = 1; d < 64; d <<= 1) {
            int t = __shfl_up(s, d, 64);
            if (lane >= d) s += t;
        }
        if (lane == 63) wsum[wid] = s;
        __syncthreads();
        if (wid == 0 && lane < 16) {
            int w = wsum[lane];
            #pragma unroll
            for (int d = 1; d < 16; d <<= 1) {
                int t = __shfl_up(w, d, 64);
                if (lane >= d) w += t;
            }
            wsum[lane] = w;
        }
        __syncthreads();
        const int wpre = (wid == 0) ? 0 : wsum[wid - 1];
        if (idx < n) offs[idx] = carry + wpre + (s - v);
        carry += wsum[15];
        __syncthreads();
    }
    if (tid == 0) offs[n] = carry;
}

__global__ __launch_bounds__(256) void dgc_edge_csr(
    const float* __restrict__ x, const float* __restrict__ ef,
    const int* __restrict__ src, const int* __restrict__ dst,
    const float* __restrict__ W1, const float* __restrict__ b1,
    const float* __restrict__ W2, const float* __restrict__ b2,
    float* __restrict__ msg, int* __restrict__ pos, int* __restrict__ deg)
{
    const int e = blockIdx.x * blockDim.x + threadIdx.x;
    if (e >= NE) return;
    float efv[16];
    {
        const float4* p = reinterpret_cast<const float4*>(ef) + (size_t)e * 4;
        float4 a = p[0], b = p[1], c = p[2], d = p[3];
        efv[0]=a.x; efv[1]=a.y; efv[2]=a.z;  efv[3]=a.w;
        efv[4]=b.x; efv[5]=b.y; efv[6]=b.z;  efv[7]=b.w;
        efv[8]=c.x; efv[9]=c.y; efv[10]=c.z; efv[11]=c.w;
        efv[12]=d.x; efv[13]=d.y; efv[14]=d.z; efv[15]=d.w;
    }
    const int s = src[e];
    float xs[16];
    {
        const float4* p = reinterpret_cast<const float4*>(x) + (size_t)s * 4;
        float4 a = p[0], b = p[1], c = p[2], d = p[3];
        xs[0]=a.x; xs[1]=a.y; xs[2]=a.z;  xs[3]=a.w;
        xs[4]=b.x; xs[5]=b.y; xs[6]=b.z;  xs[7]=b.w;
        xs[8]=c.x; xs[9]=c.y; xs[10]=c.z; xs[11]=c.w;
        xs[12]=d.x; xs[13]=d.y; xs[14]=d.z; xs[15]=d.w;
    }
    float m[16];
    #pragma unroll
    for (int o = 0; o < 16; ++o) m[o] = 0.f;
    #pragma unroll
    for (int i = 0; i < 16; ++i) {
        const float xi = xs[i];
        #pragma unroll
        for (int o = 0; o < 16; ++o) m[o] = fmaf(xi, b2[i * 16 + o], m[o]);
    }
    for (int j = 0; j < HID; ++j) {
        float hj = b1[j];
        #pragma unroll
        for (int i = 0; i < 16; ++i) hj = fmaf(efv[i], W1[i * HID + j], hj);
        hj = fmaxf(hj, 0.f);
        const float* __restrict__ w2r = W2 + (size_t)j * 256;
        float t[16];
        #pragma unroll
        for (int o = 0; o < 16; ++o) t[o] = 0.f;
        #pragma unroll
        for (int i = 0; i < 16; ++i) {
            const float xi = xs[i];
            #pragma unroll
            for (int o = 0; o < 16; ++o) t[o] = fmaf(xi, w2r[i * 16 + o], t[o]);
        }
        #pragma unroll
        for (int o = 0; o < 16; ++o) m[o] = fmaf(hj, t[o], m[o]);
    }
    float4* mr = reinterpret_cast<float4*>(msg + (size_t)e * 16);
    mr[0] = make_float4(m[0], m[1], m[2], m[3]);
    mr[1] = make_float4(m[4], m[5], m[6], m[7]);
    mr[2] = make_float4(m[8], m[9], m[10], m[11]);
    mr[3] = make_float4(m[12], m[13], m[14], m[15]);
    pos[e] = atomicAdd(deg + dst[e], 1);
}

__global__ __launch_bounds__(256) void dgc_scatter(
    const int* __restrict__ dst, const int* __restrict__ pos,
    const int* __restrict__ offs, int* __restrict__ eidx)
{
    const int e = blockIdx.x * blockDim.x + threadIdx.x;
    if (e >= NE) return;
    eidx[offs[dst[e]] + pos[e]] = e;
}

__global__ __launch_bounds__(256) void dgc_gather(
    const float* __restrict__ msg, const int* __restrict__ offs,
    const int* __restrict__ eidx, const float* __restrict__ x,
    const float* __restrict__ bias, float* __restrict__ out)
{
    const int t = blockIdx.x * blockDim.x + threadIdx.x;
    if (t >= NN * FOUT) return;
    const int n = t >> 4;
    const int o = t & 15;
    const int beg = offs[n], end = offs[n + 1];
    float s = 0.f;
    for (int k = beg; k < end; ++k)
        s += msg[(size_t)eidx[k] * 16 + o];
    const int d = end - beg;
    const float v = (d > 0) ? (s / (float)d) : x[t];
    out[t] = v + bias[o];
}

extern "C" void kernel_launch(void* const* d_in, const int* in_sizes, int n_in,
                              void* d_out, int out_size, void* d_ws, size_t ws_size,
                              hipStream_t stream) {
    const float* x    = (const float*)d_in[0];
    const float* ef   = (const float*)d_in[1];
    const int*   src  = (const int*)d_in[2];
    const int*   dst  = (const int*)d_in[3];
    const float* W1   = (const float*)d_in[4];
    const float* b1   = (const float*)d_in[5];
    const float* W2   = (const float*)d_in[6];
    const float* b2   = (const float*)d_in[7];
    const float* bias = (const float*)d_in[8];
    float* out = (float*)d_out;

    // main-path ws layout (no T buffer anymore)
    float*  msgbuf = (float*)d_ws;                        // NE*16 f32 (32 MB)
    float*  W2R    = msgbuf + (size_t)NE * 16;            // 65*256
    int*    deg_s  = (int*)(W2R + 65 * 256);              // NN
    int*    deg_d  = deg_s + NN;                          // NN
    int*    cur_d  = deg_d + NN;                          // NN
    int*    offs_s = cur_d + NN;                          // NN+1
    int*    offs_d = offs_s + NN + 1;                     // NN+1
    int*    pos_s  = offs_d + NN + 1;                     // NE
    int*    eidx_s = pos_s + NE;                          // NE
    const size_t needed =
        ((size_t)NE * 16 + 65 * 256) * 4 +
        ((size_t)3 * NN + 2 * (NN + 1) + (size_t)2 * NE) * 4;

    if (ws_size >= needed) {
        hipMemsetAsync(deg_s, 0, (size_t)3 * NN * sizeof(int), stream);  // deg_s,deg_d,cur_d
        w2r_prep<<<(65 * 256 + 255) / 256, 256, 0, stream>>>(W2, b2, W2R);
        count_both<<<(NE + 255) / 256, 256, 0, stream>>>(src, dst, deg_s, pos_s, deg_d);
        dgc_scan2<<<2, 1024, 0, stream>>>(deg_s, offs_s, deg_d, offs_d);
        scatter_src<<<(NE + 255) / 256, 256, 0, stream>>>(src, pos_s, offs_s, eidx_s);
        fused_edge<<<NN / NLB, 256, 0, stream>>>(
            x, ef, src, dst, W1, b1, W2R, eidx_s, offs_s, offs_d, cur_d, msgbuf);
        gather_mean2<<<(NN * FOUT + 255) / 256, 256, 0, stream>>>(
            msgbuf, offs_d, x, bias, out);
    } else {
        // round-2 fallback
        float* msg  = (float*)d_ws;
        int*   deg  = (int*)(msg + (size_t)NE * 16);
        int*   offs = deg + NN;
        int*   pos  = offs + NN + 1;
        int*   eidx = pos + NE;
        hipMemsetAsync(deg, 0, (size_t)NN * sizeof(int), stream);
        dgc_edge_csr<<<(NE + 255) / 256, 256, 0, stream>>>(
            x, ef, src, dst, W1, b1, W2, b2, msg, pos, deg);
        dgc_scan<<<1, 1024, 0, stream>>>(deg, offs, NN);
        dgc_scatter<<<(NE + 255) / 256, 256, 0, stream>>>(dst, pos, offs, eidx);
        dgc_gather<<<(NN * FOUT + 255) / 256, 256, 0, stream>>>(
            msg, offs, eidx, x, bias, out);
    }
}

// Round 7
// 259.918 us; speedup vs baseline: 1.4045x; 1.4045x over previous
//
#include <hip/hip_runtime.h>

#define NN 50000
#define NE 500000
#define FIN 16
#define FOUT 16
#define HID 64
#define TROW 1040   // (HID+1)*16 elems per node: j=0..63 = W2 part, j=64 = b2 part
#define NPW 16      // nodes per wave in tprep4

typedef unsigned int  uint;
typedef unsigned short ushort;

__device__ __forceinline__ ushort f2bf(float f) {   // RNE f32->bf16
    uint u = __float_as_uint(f);
    u += 0x7fffu + ((u >> 16) & 1u);
    return (ushort)(u >> 16);
}
__device__ __forceinline__ float bflo(uint u) { return __uint_as_float(u << 16); }
__device__ __forceinline__ float bfhi(uint u) { return __uint_as_float(u & 0xffff0000u); }

// ===========================================================================
// MAIN PATH (round-5 split structure, proven 288us; new tprep4).
// msg[e,o] = T[s][64][o] + sum_j h_j*T[s][j][o];  T bf16 in HBM (104 MB).
// Round-6 lesson: fused per-block phases lose to fully-parallel split kernels
// (Phase-B lane idling + occupancy). Round-5 lesson: tprep3 was latency-bound
// (27% occ, serial LDS dump) -> tprep4 = wave-per-node, stores coalesce
// per-k (lane+64k), no block syncs in hot loop, 37.4KB LDS -> 4 blocks/CU.
// ===========================================================================

// W2R[j][o][i] = W2[j][i*16+o] (j<64), b2[i*16+o] (j==64)
__global__ __launch_bounds__(256) void w2r_prep(
    const float* __restrict__ W2, const float* __restrict__ b2,
    float* __restrict__ W2R)
{
    const int t = blockIdx.x * blockDim.x + threadIdx.x;
    if (t >= 65 * 256) return;
    const int j = t >> 8;
    const int col = t & 255;          // col = i*16 + o
    const int i = col >> 4, o = col & 15;
    const float v = (j < 64) ? W2[j * 256 + col] : b2[col];
    W2R[j * 256 + o * 16 + i] = v;    // [j][o][i]
}

// one pass: src ranks (for src-sort) + dst degree histogram
__global__ __launch_bounds__(256) void count_both(
    const int* __restrict__ src, const int* __restrict__ dst,
    int* __restrict__ deg_s, int* __restrict__ pos_s, int* __restrict__ deg_d)
{
    const int e = blockIdx.x * blockDim.x + threadIdx.x;
    if (e >= NE) return;
    pos_s[e] = atomicAdd(deg_s + src[e], 1);
    atomicAdd(deg_d + dst[e], 1);
}

// two independent exclusive scans (block 0: A, block 1: B), n=NN each
__global__ __launch_bounds__(1024) void dgc_scan2(
    const int* __restrict__ degA, int* __restrict__ offA,
    const int* __restrict__ degB, int* __restrict__ offB)
{
    const int* __restrict__ deg = blockIdx.x ? degB : degA;
    int* __restrict__ offs      = blockIdx.x ? offB : offA;
    __shared__ int wsum[16];
    const int tid = threadIdx.x;
    const int lane = tid & 63;
    const int wid = tid >> 6;
    int carry = 0;
    for (int base = 0; base < NN; base += 1024) {
        const int idx = base + tid;
        const int v = (idx < NN) ? deg[idx] : 0;
        int s = v;
        #pragma unroll
        for (int d = 1; d < 64; d <<= 1) {
            int t = __shfl_up(s, d, 64);
            if (lane >= d) s += t;
        }
        if (lane == 63) wsum[wid] = s;
        __syncthreads();
        if (wid == 0 && lane < 16) {
            int w = wsum[lane];
            #pragma unroll
            for (int d = 1; d < 16; d <<= 1) {
                int t = __shfl_up(w, d, 64);
                if (lane >= d) w += t;
            }
            wsum[lane] = w;
        }
        __syncthreads();
        const int wpre = (wid == 0) ? 0 : wsum[wid - 1];
        if (idx < NN) offs[idx] = carry + wpre + (s - v);
        carry += wsum[15];
        __syncthreads();
    }
    if (tid == 0) offs[NN] = carry;
}

__global__ __launch_bounds__(256) void scatter_src(
    const int* __restrict__ src, const int* __restrict__ pos_s,
    const int* __restrict__ offs_s, int* __restrict__ eidx_s)
{
    const int e = blockIdx.x * blockDim.x + threadIdx.x;
    if (e >= NE) return;
    eidx_s[offs_s[src[e]] + pos_s[e]] = e;
}

// tprep4: one wave per node-slice. lane=(j4,o); element j*16+o = lane+64k so
// every T store is a coalesced 128B wave store. W2R staged bf16 in LDS
// [j][o][18] (pad: bank=(16*j4+9*o)%32 -> 2-way = free). No syncs in hot loop.
__global__ __launch_bounds__(256) void tprep4(
    const float* __restrict__ x, const float* __restrict__ W2R,
    ushort* __restrict__ T)
{
    __shared__ ushort w2b[65 * 288];   // [j][o*18+i], 37,440 B
    const int tid = threadIdx.x;
    for (int g = tid; g < 65 * 256; g += 256) {
        const int j = g >> 8, col = g & 255;   // col = o*16 + i
        const int oo = col >> 4, ii = col & 15;
        w2b[j * 288 + oo * 18 + ii] = f2bf(W2R[g]);
    }
    __syncthreads();

    const int w = tid >> 6, lane = tid & 63;
    const int j4 = lane >> 4, o = lane & 15;
    const int nbase = (blockIdx.x * 4 + w) * NPW;

    for (int t = 0; t < NPW; ++t) {
        const int n = nbase + t;
        if (n >= NN) break;

        float xr[16];
        {
            const float4* p = reinterpret_cast<const float4*>(x) + (size_t)n * 4;
            float4 a = p[0], b = p[1], c = p[2], d = p[3];
            xr[0]=a.x; xr[1]=a.y; xr[2]=a.z;  xr[3]=a.w;
            xr[4]=b.x; xr[5]=b.y; xr[6]=b.z;  xr[7]=b.w;
            xr[8]=c.x; xr[9]=c.y; xr[10]=c.z; xr[11]=c.w;
            xr[12]=d.x; xr[13]=d.y; xr[14]=d.z; xr[15]=d.w;
        }

        ushort* tw = T + (size_t)n * TROW;
        #pragma unroll
        for (int k = 0; k < 17; ++k) {
            const int j = j4 + (k << 2);
            if (j < 65) {
                const uint* wu = reinterpret_cast<const uint*>(w2b + j * 288 + o * 18);
                float s = 0.f;
                #pragma unroll
                for (int q = 0; q < 8; ++q) {
                    const uint u = wu[q];
                    s = fmaf(xr[2 * q],     bflo(u), s);
                    s = fmaf(xr[2 * q + 1], bfhi(u), s);
                }
                tw[j * 16 + o] = f2bf(s);
            }
        }
    }
}

// per src-sorted slot k: compute msg, write DIRECTLY to dst-sorted position.
__global__ __launch_bounds__(256) void edge_msg2(
    const int* __restrict__ eidx_s, const int* __restrict__ src,
    const int* __restrict__ dst, const float* __restrict__ ef,
    const float* __restrict__ W1, const float* __restrict__ b1,
    const ushort* __restrict__ T, const int* __restrict__ offs_d,
    int* __restrict__ cur_d, float* __restrict__ msgbuf)
{
    const int k = blockIdx.x * blockDim.x + threadIdx.x;
    if (k >= NE) return;
    const int e = eidx_s[k];
    const int s = src[e];

    float efv[16];
    {
        const float4* p = reinterpret_cast<const float4*>(ef) + (size_t)e * 4;
        float4 a = p[0], b = p[1], c = p[2], d = p[3];
        efv[0]=a.x; efv[1]=a.y; efv[2]=a.z;  efv[3]=a.w;
        efv[4]=b.x; efv[5]=b.y; efv[6]=b.z;  efv[7]=b.w;
        efv[8]=c.x; efv[9]=c.y; efv[10]=c.z; efv[11]=c.w;
        efv[12]=d.x; efv[13]=d.y; efv[14]=d.z; efv[15]=d.w;
    }

    const ushort* tr = T + (size_t)s * TROW;
    float m[16];
    {   // b2 row: j=64 -> ushort offset 1024
        uint4 a = *reinterpret_cast<const uint4*>(tr + 1024);
        uint4 b = *reinterpret_cast<const uint4*>(tr + 1032);
        m[0]=bflo(a.x);  m[1]=bfhi(a.x);  m[2]=bflo(a.y);  m[3]=bfhi(a.y);
        m[4]=bflo(a.z);  m[5]=bfhi(a.z);  m[6]=bflo(a.w);  m[7]=bfhi(a.w);
        m[8]=bflo(b.x);  m[9]=bfhi(b.x);  m[10]=bflo(b.y); m[11]=bfhi(b.y);
        m[12]=bflo(b.z); m[13]=bfhi(b.z); m[14]=bflo(b.w); m[15]=bfhi(b.w);
    }

    for (int j = 0; j < HID; ++j) {
        float hj = b1[j];
        #pragma unroll
        for (int i = 0; i < 16; ++i)
            hj = fmaf(efv[i], W1[i * HID + j], hj);
        hj = fmaxf(hj, 0.f);

        uint4 a = *reinterpret_cast<const uint4*>(tr + j * 16);
        uint4 b = *reinterpret_cast<const uint4*>(tr + j * 16 + 8);
        m[0]  = fmaf(hj, bflo(a.x), m[0]);  m[1]  = fmaf(hj, bfhi(a.x), m[1]);
        m[2]  = fmaf(hj, bflo(a.y), m[2]);  m[3]  = fmaf(hj, bfhi(a.y), m[3]);
        m[4]  = fmaf(hj, bflo(a.z), m[4]);  m[5]  = fmaf(hj, bfhi(a.z), m[5]);
        m[6]  = fmaf(hj, bflo(a.w), m[6]);  m[7]  = fmaf(hj, bfhi(a.w), m[7]);
        m[8]  = fmaf(hj, bflo(b.x), m[8]);  m[9]  = fmaf(hj, bfhi(b.x), m[9]);
        m[10] = fmaf(hj, bflo(b.y), m[10]); m[11] = fmaf(hj, bfhi(b.y), m[11]);
        m[12] = fmaf(hj, bflo(b.z), m[12]); m[13] = fmaf(hj, bfhi(b.z), m[13]);
        m[14] = fmaf(hj, bflo(b.w), m[14]); m[15] = fmaf(hj, bfhi(b.w), m[15]);
    }

    const int d = dst[e];
    const int slot = offs_d[d] + atomicAdd(cur_d + d, 1);
    float4* mr = reinterpret_cast<float4*>(msgbuf + (size_t)slot * 16);
    mr[0] = make_float4(m[0], m[1], m[2], m[3]);
    mr[1] = make_float4(m[4], m[5], m[6], m[7]);
    mr[2] = make_float4(m[8], m[9], m[10], m[11]);
    mr[3] = make_float4(m[12], m[13], m[14], m[15]);
}

// contiguous-range gather: 16 lanes per node stream deg*64B
__global__ __launch_bounds__(256) void gather_mean2(
    const float* __restrict__ msgbuf, const int* __restrict__ offs_d,
    const float* __restrict__ x, const float* __restrict__ bias,
    float* __restrict__ out)
{
    const int t = blockIdx.x * blockDim.x + threadIdx.x;
    if (t >= NN * FOUT) return;
    const int n = t >> 4;
    const int o = t & 15;
    const int beg = offs_d[n], end = offs_d[n + 1];
    float s = 0.f;
    for (int k = beg; k < end; ++k)
        s += msgbuf[(size_t)k * 16 + o];
    const int d = end - beg;
    const float v = (d > 0) ? (s / (float)d) : x[t];
    out[t] = v + bias[o];
}

// ===========================================================================
// FALLBACK (round-2 proven path, ~36.4 MB ws)
// ===========================================================================
__global__ __launch_bounds__(1024) void dgc_scan(
    const int* __restrict__ deg, int* __restrict__ offs, int n)
{
    __shared__ int wsum[16];
    const int tid = threadIdx.x;
    const int lane = tid & 63;
    const int wid = tid >> 6;
    int carry = 0;
    for (int base = 0; base < n; base += 1024) {
        const int idx = base + tid;
        const int v = (idx < n) ? deg[idx] : 0;
        int s = v;
        #pragma unroll
        for (int d = 1; d < 64; d <<= 1) {
            int t = __shfl_up(s, d, 64);
            if (lane >= d) s += t;
        }
        if (lane == 63) wsum[wid] = s;
        __syncthreads();
        if (wid == 0 && lane < 16) {
            int w = wsum[lane];
            #pragma unroll
            for (int d = 1; d < 16; d <<= 1) {
                int t = __shfl_up(w, d, 64);
                if (lane >= d) w += t;
            }
            wsum[lane] = w;
        }
        __syncthreads();
        const int wpre = (wid == 0) ? 0 : wsum[wid - 1];
        if (idx < n) offs[idx] = carry + wpre + (s - v);
        carry += wsum[15];
        __syncthreads();
    }
    if (tid == 0) offs[n] = carry;
}

__global__ __launch_bounds__(256) void dgc_edge_csr(
    const float* __restrict__ x, const float* __restrict__ ef,
    const int* __restrict__ src, const int* __restrict__ dst,
    const float* __restrict__ W1, const float* __restrict__ b1,
    const float* __restrict__ W2, const float* __restrict__ b2,
    float* __restrict__ msg, int* __restrict__ pos, int* __restrict__ deg)
{
    const int e = blockIdx.x * blockDim.x + threadIdx.x;
    if (e >= NE) return;
    float efv[16];
    {
        const float4* p = reinterpret_cast<const float4*>(ef) + (size_t)e * 4;
        float4 a = p[0], b = p[1], c = p[2], d = p[3];
        efv[0]=a.x; efv[1]=a.y; efv[2]=a.z;  efv[3]=a.w;
        efv[4]=b.x; efv[5]=b.y; efv[6]=b.z;  efv[7]=b.w;
        efv[8]=c.x; efv[9]=c.y; efv[10]=c.z; efv[11]=c.w;
        efv[12]=d.x; efv[13]=d.y; efv[14]=d.z; efv[15]=d.w;
    }
    const int s = src[e];
    float xs[16];
    {
        const float4* p = reinterpret_cast<const float4*>(x) + (size_t)s * 4;
        float4 a = p[0], b = p[1], c = p[2], d = p[3];
        xs[0]=a.x; xs[1]=a.y; xs[2]=a.z;  xs[3]=a.w;
        xs[4]=b.x; xs[5]=b.y; xs[6]=b.z;  xs[7]=b.w;
        xs[8]=c.x; xs[9]=c.y; xs[10]=c.z; xs[11]=c.w;
        xs[12]=d.x; xs[13]=d.y; xs[14]=d.z; xs[15]=d.w;
    }
    float m[16];
    #pragma unroll
    for (int o = 0; o < 16; ++o) m[o] = 0.f;
    #pragma unroll
    for (int i = 0; i < 16; ++i) {
        const float xi = xs[i];
        #pragma unroll
        for (int o = 0; o < 16; ++o) m[o] = fmaf(xi, b2[i * 16 + o], m[o]);
    }
    for (int j = 0; j < HID; ++j) {
        float hj = b1[j];
        #pragma unroll
        for (int i = 0; i < 16; ++i) hj = fmaf(efv[i], W1[i * HID + j], hj);
        hj = fmaxf(hj, 0.f);
        const float* __restrict__ w2r = W2 + (size_t)j * 256;
        float t[16];
        #pragma unroll
        for (int o = 0; o < 16; ++o) t[o] = 0.f;
        #pragma unroll
        for (int i = 0; i < 16; ++i) {
            const float xi = xs[i];
            #pragma unroll
            for (int o = 0; o < 16; ++o) t[o] = fmaf(xi, w2r[i * 16 + o], t[o]);
        }
        #pragma unroll
        for (int o = 0; o < 16; ++o) m[o] = fmaf(hj, t[o], m[o]);
    }
    float4* mr = reinterpret_cast<float4*>(msg + (size_t)e * 16);
    mr[0] = make_float4(m[0], m[1], m[2], m[3]);
    mr[1] = make_float4(m[4], m[5], m[6], m[7]);
    mr[2] = make_float4(m[8], m[9], m[10], m[11]);
    mr[3] = make_float4(m[12], m[13], m[14], m[15]);
    pos[e] = atomicAdd(deg + dst[e], 1);
}

__global__ __launch_bounds__(256) void dgc_scatter(
    const int* __restrict__ dst, const int* __restrict__ pos,
    const int* __restrict__ offs, int* __restrict__ eidx)
{
    const int e = blockIdx.x * blockDim.x + threadIdx.x;
    if (e >= NE) return;
    eidx[offs[dst[e]] + pos[e]] = e;
}

__global__ __launch_bounds__(256) void dgc_gather(
    const float* __restrict__ msg, const int* __restrict__ offs,
    const int* __restrict__ eidx, const float* __restrict__ x,
    const float* __restrict__ bias, float* __restrict__ out)
{
    const int t = blockIdx.x * blockDim.x + threadIdx.x;
    if (t >= NN * FOUT) return;
    const int n = t >> 4;
    const int o = t & 15;
    const int beg = offs[n], end = offs[n + 1];
    float s = 0.f;
    for (int k = beg; k < end; ++k)
        s += msg[(size_t)eidx[k] * 16 + o];
    const int d = end - beg;
    const float v = (d > 0) ? (s / (float)d) : x[t];
    out[t] = v + bias[o];
}

extern "C" void kernel_launch(void* const* d_in, const int* in_sizes, int n_in,
                              void* d_out, int out_size, void* d_ws, size_t ws_size,
                              hipStream_t stream) {
    const float* x    = (const float*)d_in[0];
    const float* ef   = (const float*)d_in[1];
    const int*   src  = (const int*)d_in[2];
    const int*   dst  = (const int*)d_in[3];
    const float* W1   = (const float*)d_in[4];
    const float* b1   = (const float*)d_in[5];
    const float* W2   = (const float*)d_in[6];
    const float* b2   = (const float*)d_in[7];
    const float* bias = (const float*)d_in[8];
    float* out = (float*)d_out;

    // main-path ws layout
    ushort* T      = (ushort*)d_ws;                       // NN*TROW bf16 (104 MB)
    float*  msgbuf = (float*)(T + (size_t)NN * TROW);     // NE*16 f32   (32 MB)
    float*  W2R    = msgbuf + (size_t)NE * 16;            // 65*256
    int*    deg_s  = (int*)(W2R + 65 * 256);              // NN
    int*    deg_d  = deg_s + NN;                          // NN
    int*    cur_d  = deg_d + NN;                          // NN
    int*    offs_s = cur_d + NN;                          // NN+1
    int*    offs_d = offs_s + NN + 1;                     // NN+1
    int*    pos_s  = offs_d + NN + 1;                     // NE
    int*    eidx_s = pos_s + NE;                          // NE
    const size_t needed =
        (size_t)NN * TROW * 2 +
        ((size_t)NE * 16 + 65 * 256) * 4 +
        ((size_t)3 * NN + 2 * (NN + 1) + (size_t)2 * NE) * 4;

    if (ws_size >= needed) {
        hipMemsetAsync(deg_s, 0, (size_t)3 * NN * sizeof(int), stream);  // deg_s,deg_d,cur_d
        w2r_prep<<<(65 * 256 + 255) / 256, 256, 0, stream>>>(W2, b2, W2R);
        count_both<<<(NE + 255) / 256, 256, 0, stream>>>(src, dst, deg_s, pos_s, deg_d);
        dgc_scan2<<<2, 1024, 0, stream>>>(deg_s, offs_s, deg_d, offs_d);
        scatter_src<<<(NE + 255) / 256, 256, 0, stream>>>(src, pos_s, offs_s, eidx_s);
        tprep4<<<(NN + 4 * NPW - 1) / (4 * NPW), 256, 0, stream>>>(x, W2R, T);
        edge_msg2<<<(NE + 255) / 256, 256, 0, stream>>>(
            eidx_s, src, dst, ef, W1, b1, T, offs_d, cur_d, msgbuf);
        gather_mean2<<<(NN * FOUT + 255) / 256, 256, 0, stream>>>(
            msgbuf, offs_d, x, bias, out);
    } else {
        // round-2 fallback
        float* msg  = (float*)d_ws;
        int*   deg  = (int*)(msg + (size_t)NE * 16);
        int*   offs = deg + NN;
        int*   pos  = offs + NN + 1;
        int*   eidx = pos + NE;
        hipMemsetAsync(deg, 0, (size_t)NN * sizeof(int), stream);
        dgc_edge_csr<<<(NE + 255) / 256, 256, 0, stream>>>(
            x, ef, src, dst, W1, b1, W2, b2, msg, pos, deg);
        dgc_scan<<<1, 1024, 0, stream>>>(deg, offs, NN);
        dgc_scatter<<<(NE + 255) / 256, 256, 0, stream>>>(dst, pos, offs, eidx);
        dgc_gather<<<(NN * FOUT + 255) / 256, 256, 0, stream>>>(
            msg, offs, eidx, x, bias, out);
    }
}

// Round 8
// 233.240 us; speedup vs baseline: 1.5651x; 1.1144x over previous
//
#include <hip/hip_runtime.h>

#define NN 50000
#define NE 500000
#define FIN 16
#define FOUT 16
#define HID 64
#define TROW 1040   // (HID+1)*16 elems per node: j=0..63 = W2 part, j=64 = b2 part

typedef unsigned int  uint;
typedef unsigned short ushort;

__device__ __forceinline__ ushort f2bf(float f) {   // RNE f32->bf16
    uint u = __float_as_uint(f);
    u += 0x7fffu + ((u >> 16) & 1u);
    return (ushort)(u >> 16);
}
__device__ __forceinline__ float bflo(uint u) { return __uint_as_float(u << 16); }
__device__ __forceinline__ float bfhi(uint u) { return __uint_as_float(u & 0xffff0000u); }

// ===========================================================================
// MAIN PATH. Round-7 lessons: tprep4 grid too small (782 blocks, 27% occ) +
// bf16 unpack VALU tax -> tprep5 holds W2 in REGISTERS (f32), grid-stride,
// coalesced 2B stores, zero LDS. edge_msg2 was latency-bound (VALU 43%,
// 1.45TB/s fetch) -> edge_msg3 does 2 consecutive slots/thread for 2x ILP
// (independent h-chains + accumulators; shared-src T lines hit L1).
// ===========================================================================

// W2R[j][o][i] = W2[j][i*16+o] (j<64), b2[i*16+o] (j==64)
__global__ __launch_bounds__(256) void w2r_prep(
    const float* __restrict__ W2, const float* __restrict__ b2,
    float* __restrict__ W2R)
{
    const int t = blockIdx.x * blockDim.x + threadIdx.x;
    if (t >= 65 * 256) return;
    const int j = t >> 8;
    const int col = t & 255;          // col = i*16 + o
    const int i = col >> 4, o = col & 15;
    const float v = (j < 64) ? W2[j * 256 + col] : b2[col];
    W2R[j * 256 + o * 16 + i] = v;    // [j][o][i]
}

// one pass: src ranks (for src-sort) + dst degree histogram
__global__ __launch_bounds__(256) void count_both(
    const int* __restrict__ src, const int* __restrict__ dst,
    int* __restrict__ deg_s, int* __restrict__ pos_s, int* __restrict__ deg_d)
{
    const int e = blockIdx.x * blockDim.x + threadIdx.x;
    if (e >= NE) return;
    pos_s[e] = atomicAdd(deg_s + src[e], 1);
    atomicAdd(deg_d + dst[e], 1);
}

// two independent exclusive scans (block 0: A, block 1: B), n=NN each
__global__ __launch_bounds__(1024) void dgc_scan2(
    const int* __restrict__ degA, int* __restrict__ offA,
    const int* __restrict__ degB, int* __restrict__ offB)
{
    const int* __restrict__ deg = blockIdx.x ? degB : degA;
    int* __restrict__ offs      = blockIdx.x ? offB : offA;
    __shared__ int wsum[16];
    const int tid = threadIdx.x;
    const int lane = tid & 63;
    const int wid = tid >> 6;
    int carry = 0;
    for (int base = 0; base < NN; base += 1024) {
        const int idx = base + tid;
        const int v = (idx < NN) ? deg[idx] : 0;
        int s = v;
        #pragma unroll
        for (int d = 1; d < 64; d <<= 1) {
            int t = __shfl_up(s, d, 64);
            if (lane >= d) s += t;
        }
        if (lane == 63) wsum[wid] = s;
        __syncthreads();
        if (wid == 0 && lane < 16) {
            int w = wsum[lane];
            #pragma unroll
            for (int d = 1; d < 16; d <<= 1) {
                int t = __shfl_up(w, d, 64);
                if (lane >= d) w += t;
            }
            wsum[lane] = w;
        }
        __syncthreads();
        const int wpre = (wid == 0) ? 0 : wsum[wid - 1];
        if (idx < NN) offs[idx] = carry + wpre + (s - v);
        carry += wsum[15];
        __syncthreads();
    }
    if (tid == 0) offs[NN] = carry;
}

__global__ __launch_bounds__(256) void scatter_src(
    const int* __restrict__ src, const int* __restrict__ pos_s,
    const int* __restrict__ offs_s, int* __restrict__ eidx_s)
{
    const int e = blockIdx.x * blockDim.x + threadIdx.x;
    if (e >= NE) return;
    eidx_s[offs_s[src[e]] + pos_s[e]] = e;
}

// tprep5: thread (jt,o) owns W2R rows {jt, jt+16, jt+32, jt+48} (64 f32 regs,
// loaded once per block); x row wave-uniform (s_load); T stores coalesce as
// tid+256r. Grid-stride over nodes, no LDS, no syncs.
__global__ __launch_bounds__(256) void tprep5(
    const float* __restrict__ x, const float* __restrict__ W2R,
    ushort* __restrict__ T)
{
    const int tid = threadIdx.x;
    const int jt = tid >> 4, o = tid & 15;

    float w0[16], w1[16], w2[16], w3[16];
    {
        const float4* p0 = reinterpret_cast<const float4*>(W2R + (jt     ) * 256 + o * 16);
        const float4* p1 = reinterpret_cast<const float4*>(W2R + (jt + 16) * 256 + o * 16);
        const float4* p2 = reinterpret_cast<const float4*>(W2R + (jt + 32) * 256 + o * 16);
        const float4* p3 = reinterpret_cast<const float4*>(W2R + (jt + 48) * 256 + o * 16);
        #pragma unroll
        for (int q = 0; q < 4; ++q) {
            float4 a = p0[q]; w0[4*q]=a.x; w0[4*q+1]=a.y; w0[4*q+2]=a.z; w0[4*q+3]=a.w;
            float4 b = p1[q]; w1[4*q]=b.x; w1[4*q+1]=b.y; w1[4*q+2]=b.z; w1[4*q+3]=b.w;
            float4 c = p2[q]; w2[4*q]=c.x; w2[4*q+1]=c.y; w2[4*q+2]=c.z; w2[4*q+3]=c.w;
            float4 d = p3[q]; w3[4*q]=d.x; w3[4*q+1]=d.y; w3[4*q+2]=d.z; w3[4*q+3]=d.w;
        }
    }
    float wb[16];
    if (jt == 0) {
        const float4* pb = reinterpret_cast<const float4*>(W2R + 64 * 256 + o * 16);
        #pragma unroll
        for (int q = 0; q < 4; ++q) {
            float4 a = pb[q]; wb[4*q]=a.x; wb[4*q+1]=a.y; wb[4*q+2]=a.z; wb[4*q+3]=a.w;
        }
    }

    for (int n = blockIdx.x; n < NN; n += gridDim.x) {
        float xr[16];
        {
            const float4* p = reinterpret_cast<const float4*>(x) + (size_t)n * 4;
            float4 a = p[0], b = p[1], c = p[2], d = p[3];
            xr[0]=a.x; xr[1]=a.y; xr[2]=a.z;  xr[3]=a.w;
            xr[4]=b.x; xr[5]=b.y; xr[6]=b.z;  xr[7]=b.w;
            xr[8]=c.x; xr[9]=c.y; xr[10]=c.z; xr[11]=c.w;
            xr[12]=d.x; xr[13]=d.y; xr[14]=d.z; xr[15]=d.w;
        }
        ushort* tw = T + (size_t)n * TROW;

        float s0 = xr[0]*w0[0], s1 = xr[0]*w1[0], s2 = xr[0]*w2[0], s3 = xr[0]*w3[0];
        #pragma unroll
        for (int i = 1; i < 16; ++i) {
            s0 = fmaf(xr[i], w0[i], s0);
            s1 = fmaf(xr[i], w1[i], s1);
            s2 = fmaf(xr[i], w2[i], s2);
            s3 = fmaf(xr[i], w3[i], s3);
        }
        tw[tid]       = f2bf(s0);
        tw[tid + 256] = f2bf(s1);
        tw[tid + 512] = f2bf(s2);
        tw[tid + 768] = f2bf(s3);
        if (jt == 0) {
            float sb = xr[0]*wb[0];
            #pragma unroll
            for (int i = 1; i < 16; ++i) sb = fmaf(xr[i], wb[i], sb);
            tw[1024 + o] = f2bf(sb);
        }
    }
}

// edge_msg3: two consecutive src-sorted slots per thread (2x ILP; shared-src
// T lines L1-hit). Writes DIRECTLY to dst-sorted positions.
__global__ __launch_bounds__(256) void edge_msg3(
    const int* __restrict__ eidx_s, const int* __restrict__ src,
    const int* __restrict__ dst, const float* __restrict__ ef,
    const float* __restrict__ W1, const float* __restrict__ b1,
    const ushort* __restrict__ T, const int* __restrict__ offs_d,
    int* __restrict__ cur_d, float* __restrict__ msgbuf)
{
    const int k0 = (blockIdx.x * blockDim.x + threadIdx.x) * 2;
    if (k0 >= NE) return;
    const bool two = (k0 + 1 < NE);
    const int k1 = two ? (k0 + 1) : k0;

    const int e0 = eidx_s[k0], e1 = eidx_s[k1];
    const int s0 = src[e0],    s1 = src[e1];

    float ea[16], eb[16];
    {
        const float4* p = reinterpret_cast<const float4*>(ef) + (size_t)e0 * 4;
        float4 a = p[0], b = p[1], c = p[2], d = p[3];
        ea[0]=a.x; ea[1]=a.y; ea[2]=a.z;  ea[3]=a.w;
        ea[4]=b.x; ea[5]=b.y; ea[6]=b.z;  ea[7]=b.w;
        ea[8]=c.x; ea[9]=c.y; ea[10]=c.z; ea[11]=c.w;
        ea[12]=d.x; ea[13]=d.y; ea[14]=d.z; ea[15]=d.w;
    }
    {
        const float4* p = reinterpret_cast<const float4*>(ef) + (size_t)e1 * 4;
        float4 a = p[0], b = p[1], c = p[2], d = p[3];
        eb[0]=a.x; eb[1]=a.y; eb[2]=a.z;  eb[3]=a.w;
        eb[4]=b.x; eb[5]=b.y; eb[6]=b.z;  eb[7]=b.w;
        eb[8]=c.x; eb[9]=c.y; eb[10]=c.z; eb[11]=c.w;
        eb[12]=d.x; eb[13]=d.y; eb[14]=d.z; eb[15]=d.w;
    }

    const ushort* tr0 = T + (size_t)s0 * TROW;
    const ushort* tr1 = T + (size_t)s1 * TROW;

    float m0[16], m1[16];
    {
        uint4 a = *reinterpret_cast<const uint4*>(tr0 + 1024);
        uint4 b = *reinterpret_cast<const uint4*>(tr0 + 1032);
        m0[0]=bflo(a.x);  m0[1]=bfhi(a.x);  m0[2]=bflo(a.y);  m0[3]=bfhi(a.y);
        m0[4]=bflo(a.z);  m0[5]=bfhi(a.z);  m0[6]=bflo(a.w);  m0[7]=bfhi(a.w);
        m0[8]=bflo(b.x);  m0[9]=bfhi(b.x);  m0[10]=bflo(b.y); m0[11]=bfhi(b.y);
        m0[12]=bflo(b.z); m0[13]=bfhi(b.z); m0[14]=bflo(b.w); m0[15]=bfhi(b.w);
    }
    {
        uint4 a = *reinterpret_cast<const uint4*>(tr1 + 1024);
        uint4 b = *reinterpret_cast<const uint4*>(tr1 + 1032);
        m1[0]=bflo(a.x);  m1[1]=bfhi(a.x);  m1[2]=bflo(a.y);  m1[3]=bfhi(a.y);
        m1[4]=bflo(a.z);  m1[5]=bfhi(a.z);  m1[6]=bflo(a.w);  m1[7]=bfhi(a.w);
        m1[8]=bflo(b.x);  m1[9]=bfhi(b.x);  m1[10]=bflo(b.y); m1[11]=bfhi(b.y);
        m1[12]=bflo(b.z); m1[13]=bfhi(b.z); m1[14]=bflo(b.w); m1[15]=bfhi(b.w);
    }

    for (int j = 0; j < HID; ++j) {
        float h0 = b1[j], h1 = h0;
        #pragma unroll
        for (int i = 0; i < 16; ++i) {
            const float w = W1[i * HID + j];
            h0 = fmaf(ea[i], w, h0);
            h1 = fmaf(eb[i], w, h1);
        }
        h0 = fmaxf(h0, 0.f);
        h1 = fmaxf(h1, 0.f);

        uint4 a0 = *reinterpret_cast<const uint4*>(tr0 + j * 16);
        uint4 b0 = *reinterpret_cast<const uint4*>(tr0 + j * 16 + 8);
        uint4 a1 = *reinterpret_cast<const uint4*>(tr1 + j * 16);
        uint4 b1v = *reinterpret_cast<const uint4*>(tr1 + j * 16 + 8);
        m0[0]  = fmaf(h0, bflo(a0.x), m0[0]);  m0[1]  = fmaf(h0, bfhi(a0.x), m0[1]);
        m0[2]  = fmaf(h0, bflo(a0.y), m0[2]);  m0[3]  = fmaf(h0, bfhi(a0.y), m0[3]);
        m0[4]  = fmaf(h0, bflo(a0.z), m0[4]);  m0[5]  = fmaf(h0, bfhi(a0.z), m0[5]);
        m0[6]  = fmaf(h0, bflo(a0.w), m0[6]);  m0[7]  = fmaf(h0, bfhi(a0.w), m0[7]);
        m0[8]  = fmaf(h0, bflo(b0.x), m0[8]);  m0[9]  = fmaf(h0, bfhi(b0.x), m0[9]);
        m0[10] = fmaf(h0, bflo(b0.y), m0[10]); m0[11] = fmaf(h0, bfhi(b0.y), m0[11]);
        m0[12] = fmaf(h0, bflo(b0.z), m0[12]); m0[13] = fmaf(h0, bfhi(b0.z), m0[13]);
        m0[14] = fmaf(h0, bflo(b0.w), m0[14]); m0[15] = fmaf(h0, bfhi(b0.w), m0[15]);
        m1[0]  = fmaf(h1, bflo(a1.x), m1[0]);  m1[1]  = fmaf(h1, bfhi(a1.x), m1[1]);
        m1[2]  = fmaf(h1, bflo(a1.y), m1[2]);  m1[3]  = fmaf(h1, bfhi(a1.y), m1[3]);
        m1[4]  = fmaf(h1, bflo(a1.z), m1[4]);  m1[5]  = fmaf(h1, bfhi(a1.z), m1[5]);
        m1[6]  = fmaf(h1, bflo(a1.w), m1[6]);  m1[7]  = fmaf(h1, bfhi(a1.w), m1[7]);
        m1[8]  = fmaf(h1, bflo(b1v.x), m1[8]);  m1[9]  = fmaf(h1, bfhi(b1v.x), m1[9]);
        m1[10] = fmaf(h1, bflo(b1v.y), m1[10]); m1[11] = fmaf(h1, bfhi(b1v.y), m1[11]);
        m1[12] = fmaf(h1, bflo(b1v.z), m1[12]); m1[13] = fmaf(h1, bfhi(b1v.z), m1[13]);
        m1[14] = fmaf(h1, bflo(b1v.w), m1[14]); m1[15] = fmaf(h1, bfhi(b1v.w), m1[15]);
    }

    {
        const int d = dst[e0];
        const int slot = offs_d[d] + atomicAdd(cur_d + d, 1);
        float4* mr = reinterpret_cast<float4*>(msgbuf + (size_t)slot * 16);
        mr[0] = make_float4(m0[0], m0[1], m0[2], m0[3]);
        mr[1] = make_float4(m0[4], m0[5], m0[6], m0[7]);
        mr[2] = make_float4(m0[8], m0[9], m0[10], m0[11]);
        mr[3] = make_float4(m0[12], m0[13], m0[14], m0[15]);
    }
    if (two) {
        const int d = dst[e1];
        const int slot = offs_d[d] + atomicAdd(cur_d + d, 1);
        float4* mr = reinterpret_cast<float4*>(msgbuf + (size_t)slot * 16);
        mr[0] = make_float4(m1[0], m1[1], m1[2], m1[3]);
        mr[1] = make_float4(m1[4], m1[5], m1[6], m1[7]);
        mr[2] = make_float4(m1[8], m1[9], m1[10], m1[11]);
        mr[3] = make_float4(m1[12], m1[13], m1[14], m1[15]);
    }
}

// contiguous-range gather: 16 lanes per node stream deg*64B
__global__ __launch_bounds__(256) void gather_mean2(
    const float* __restrict__ msgbuf, const int* __restrict__ offs_d,
    const float* __restrict__ x, const float* __restrict__ bias,
    float* __restrict__ out)
{
    const int t = blockIdx.x * blockDim.x + threadIdx.x;
    if (t >= NN * FOUT) return;
    const int n = t >> 4;
    const int o = t & 15;
    const int beg = offs_d[n], end = offs_d[n + 1];
    float s = 0.f;
    for (int k = beg; k < end; ++k)
        s += msgbuf[(size_t)k * 16 + o];
    const int d = end - beg;
    const float v = (d > 0) ? (s / (float)d) : x[t];
    out[t] = v + bias[o];
}

// ===========================================================================
// FALLBACK (round-2 proven path, ~36.4 MB ws)
// ===========================================================================
__global__ __launch_bounds__(1024) void dgc_scan(
    const int* __restrict__ deg, int* __restrict__ offs, int n)
{
    __shared__ int wsum[16];
    const int tid = threadIdx.x;
    const int lane = tid & 63;
    const int wid = tid >> 6;
    int carry = 0;
    for (int base = 0; base < n; base += 1024) {
        const int idx = base + tid;
        const int v = (idx < n) ? deg[idx] : 0;
        int s = v;
        #pragma unroll
        for (int d = 1; d < 64; d <<= 1) {
            int t = __shfl_up(s, d, 64);
            if (lane >= d) s += t;
        }
        if (lane == 63) wsum[wid] = s;
        __syncthreads();
        if (wid == 0 && lane < 16) {
            int w = wsum[lane];
            #pragma unroll
            for (int d = 1; d < 16; d <<= 1) {
                int t = __shfl_up(w, d, 64);
                if (lane >= d) w += t;
            }
            wsum[lane] = w;
        }
        __syncthreads();
        const int wpre = (wid == 0) ? 0 : wsum[wid - 1];
        if (idx < n) offs[idx] = carry + wpre + (s - v);
        carry += wsum[15];
        __syncthreads();
    }
    if (tid == 0) offs[n] = carry;
}

__global__ __launch_bounds__(256) void dgc_edge_csr(
    const float* __restrict__ x, const float* __restrict__ ef,
    const int* __restrict__ src, const int* __restrict__ dst,
    const float* __restrict__ W1, const float* __restrict__ b1,
    const float* __restrict__ W2, const float* __restrict__ b2,
    float* __restrict__ msg, int* __restrict__ pos, int* __restrict__ deg)
{
    const int e = blockIdx.x * blockDim.x + threadIdx.x;
    if (e >= NE) return;
    float efv[16];
    {
        const float4* p = reinterpret_cast<const float4*>(ef) + (size_t)e * 4;
        float4 a = p[0], b = p[1], c = p[2], d = p[3];
        efv[0]=a.x; efv[1]=a.y; efv[2]=a.z;  efv[3]=a.w;
        efv[4]=b.x; efv[5]=b.y; efv[6]=b.z;  efv[7]=b.w;
        efv[8]=c.x; efv[9]=c.y; efv[10]=c.z; efv[11]=c.w;
        efv[12]=d.x; efv[13]=d.y; efv[14]=d.z; efv[15]=d.w;
    }
    const int s = src[e];
    float xs[16];
    {
        const float4* p = reinterpret_cast<const float4*>(x) + (size_t)s * 4;
        float4 a = p[0], b = p[1], c = p[2], d = p[3];
        xs[0]=a.x; xs[1]=a.y; xs[2]=a.z;  xs[3]=a.w;
        xs[4]=b.x; xs[5]=b.y; xs[6]=b.z;  xs[7]=b.w;
        xs[8]=c.x; xs[9]=c.y; xs[10]=c.z; xs[11]=c.w;
        xs[12]=d.x; xs[13]=d.y; xs[14]=d.z; xs[15]=d.w;
    }
    float m[16];
    #pragma unroll
    for (int o = 0; o < 16; ++o) m[o] = 0.f;
    #pragma unroll
    for (int i = 0; i < 16; ++i) {
        const float xi = xs[i];
        #pragma unroll
        for (int o = 0; o < 16; ++o) m[o] = fmaf(xi, b2[i * 16 + o], m[o]);
    }
    for (int j = 0; j < HID; ++j) {
        float hj = b1[j];
        #pragma unroll
        for (int i = 0; i < 16; ++i) hj = fmaf(efv[i], W1[i * HID + j], hj);
        hj = fmaxf(hj, 0.f);
        const float* __restrict__ w2r = W2 + (size_t)j * 256;
        float t[16];
        #pragma unroll
        for (int o = 0; o < 16; ++o) t[o] = 0.f;
        #pragma unroll
        for (int i = 0; i < 16; ++i) {
            const float xi = xs[i];
            #pragma unroll
            for (int o = 0; o < 16; ++o) t[o] = fmaf(xi, w2r[i * 16 + o], t[o]);
        }
        #pragma unroll
        for (int o = 0; o < 16; ++o) m[o] = fmaf(hj, t[o], m[o]);
    }
    float4* mr = reinterpret_cast<float4*>(msg + (size_t)e * 16);
    mr[0] = make_float4(m[0], m[1], m[2], m[3]);
    mr[1] = make_float4(m[4], m[5], m[6], m[7]);
    mr[2] = make_float4(m[8], m[9], m[10], m[11]);
    mr[3] = make_float4(m[12], m[13], m[14], m[15]);
    pos[e] = atomicAdd(deg + dst[e], 1);
}

__global__ __launch_bounds__(256) void dgc_scatter(
    const int* __restrict__ dst, const int* __restrict__ pos,
    const int* __restrict__ offs, int* __restrict__ eidx)
{
    const int e = blockIdx.x * blockDim.x + threadIdx.x;
    if (e >= NE) return;
    eidx[offs[dst[e]] + pos[e]] = e;
}

__global__ __launch_bounds__(256) void dgc_gather(
    const float* __restrict__ msg, const int* __restrict__ offs,
    const int* __restrict__ eidx, const float* __restrict__ x,
    const float* __restrict__ bias, float* __restrict__ out)
{
    const int t = blockIdx.x * blockDim.x + threadIdx.x;
    if (t >= NN * FOUT) return;
    const int n = t >> 4;
    const int o = t & 15;
    const int beg = offs[n], end = offs[n + 1];
    float s = 0.f;
    for (int k = beg; k < end; ++k)
        s += msg[(size_t)eidx[k] * 16 + o];
    const int d = end - beg;
    const float v = (d > 0) ? (s / (float)d) : x[t];
    out[t] = v + bias[o];
}

extern "C" void kernel_launch(void* const* d_in, const int* in_sizes, int n_in,
                              void* d_out, int out_size, void* d_ws, size_t ws_size,
                              hipStream_t stream) {
    const float* x    = (const float*)d_in[0];
    const float* ef   = (const float*)d_in[1];
    const int*   src  = (const int*)d_in[2];
    const int*   dst  = (const int*)d_in[3];
    const float* W1   = (const float*)d_in[4];
    const float* b1   = (const float*)d_in[5];
    const float* W2   = (const float*)d_in[6];
    const float* b2   = (const float*)d_in[7];
    const float* bias = (const float*)d_in[8];
    float* out = (float*)d_out;

    // main-path ws layout
    ushort* T      = (ushort*)d_ws;                       // NN*TROW bf16 (104 MB)
    float*  msgbuf = (float*)(T + (size_t)NN * TROW);     // NE*16 f32   (32 MB)
    float*  W2R    = msgbuf + (size_t)NE * 16;            // 65*256
    int*    deg_s  = (int*)(W2R + 65 * 256);              // NN
    int*    deg_d  = deg_s + NN;                          // NN
    int*    cur_d  = deg_d + NN;                          // NN
    int*    offs_s = cur_d + NN;                          // NN+1
    int*    offs_d = offs_s + NN + 1;                     // NN+1
    int*    pos_s  = offs_d + NN + 1;                     // NE
    int*    eidx_s = pos_s + NE;                          // NE
    const size_t needed =
        (size_t)NN * TROW * 2 +
        ((size_t)NE * 16 + 65 * 256) * 4 +
        ((size_t)3 * NN + 2 * (NN + 1) + (size_t)2 * NE) * 4;

    if (ws_size >= needed) {
        hipMemsetAsync(deg_s, 0, (size_t)3 * NN * sizeof(int), stream);  // deg_s,deg_d,cur_d
        w2r_prep<<<(65 * 256 + 255) / 256, 256, 0, stream>>>(W2, b2, W2R);
        count_both<<<(NE + 255) / 256, 256, 0, stream>>>(src, dst, deg_s, pos_s, deg_d);
        dgc_scan2<<<2, 1024, 0, stream>>>(deg_s, offs_s, deg_d, offs_d);
        scatter_src<<<(NE + 255) / 256, 256, 0, stream>>>(src, pos_s, offs_s, eidx_s);
        tprep5<<<2048, 256, 0, stream>>>(x, W2R, T);
        edge_msg3<<<(NE / 2 + 255) / 256, 256, 0, stream>>>(
            eidx_s, src, dst, ef, W1, b1, T, offs_d, cur_d, msgbuf);
        gather_mean2<<<(NN * FOUT + 255) / 256, 256, 0, stream>>>(
            msgbuf, offs_d, x, bias, out);
    } else {
        // round-2 fallback
        float* msg  = (float*)d_ws;
        int*   deg  = (int*)(msg + (size_t)NE * 16);
        int*   offs = deg + NN;
        int*   pos  = offs + NN + 1;
        int*   eidx = pos + NE;
        hipMemsetAsync(deg, 0, (size_t)NN * sizeof(int), stream);
        dgc_edge_csr<<<(NE + 255) / 256, 256, 0, stream>>>(
            x, ef, src, dst, W1, b1, W2, b2, msg, pos, deg);
        dgc_scan<<<1, 1024, 0, stream>>>(deg, offs, NN);
        dgc_scatter<<<(NE + 255) / 256, 256, 0, stream>>>(dst, pos, offs, eidx);
        dgc_gather<<<(NN * FOUT + 255) / 256, 256, 0, stream>>>(
            msg, offs, eidx, x, bias, out);
    }
}